// Round 4
// baseline (1239.537 us; speedup 1.0000x reference)
//
#include <hip/hip_runtime.h>

#define N_NODES 81920
#define N_EDGES 1310720
#define NG 256
#define D 64
#define TM 64
#define SA 65   // LDS row stride: bank=(row+lane)%32 -> uniform 2-way alias (free)

// ---------------- small utility kernels ----------------

__global__ void zero_ints(int* __restrict__ p, int n) {
    int i = blockIdx.x * blockDim.x + threadIdx.x;
    if (i < n) p[i] = 0;
}

__global__ void zero_f4(float4* __restrict__ p, int n4) {
    int i = blockIdx.x * blockDim.x + threadIdx.x;
    if (i < n4) p[i] = make_float4(0.f, 0.f, 0.f, 0.f);
}

__global__ void count_at(const int* __restrict__ idx, int* __restrict__ cnt) {
    int e = blockIdx.x * blockDim.x + threadIdx.x;
    if (e < N_EDGES) atomicAdd(&cnt[idx[e]], 1);   // fire-and-forget int atomic
}

__global__ void scan_block(const int* __restrict__ cnt, int* __restrict__ row_ptr,
                           int* __restrict__ bsums) {
    __shared__ int s[256];
    int tid = threadIdx.x;
    int i = blockIdx.x * 256 + tid;
    int v = cnt[i];
    s[tid] = v;
    __syncthreads();
    for (int ofs = 1; ofs < 256; ofs <<= 1) {
        int t = (tid >= ofs) ? s[tid - ofs] : 0;
        __syncthreads();
        s[tid] += t;
        __syncthreads();
    }
    row_ptr[i] = s[tid] - v;               // exclusive
    if (tid == 255) bsums[blockIdx.x] = s[255];
}

__global__ void scan_top(int* __restrict__ bsums) {   // 320 entries, 1 block x 512
    __shared__ int s[512];
    int tid = threadIdx.x;
    int v = (tid < 320) ? bsums[tid] : 0;
    s[tid] = v;
    __syncthreads();
    for (int ofs = 1; ofs < 512; ofs <<= 1) {
        int t = (tid >= ofs) ? s[tid - ofs] : 0;
        __syncthreads();
        s[tid] += t;
        __syncthreads();
    }
    if (tid < 320) bsums[tid] = s[tid] - v; // exclusive
}

__global__ void add_offsets(int* __restrict__ row_ptr, const int* __restrict__ bsums) {
    int i = blockIdx.x * 256 + threadIdx.x;
    row_ptr[i] += bsums[blockIdx.x];
    if (i == 0) row_ptr[N_NODES] = N_EDGES;
}

// CSR by src; pack (dst<<6)|(src&63): dst < 2^17, 6 bits of src-within-block
__global__ void bucket_src(const int* __restrict__ src, const int* __restrict__ dst,
                           const int* __restrict__ row_ptr, int* __restrict__ cur,
                           int* __restrict__ esp) {
    int e = blockIdx.x * blockDim.x + threadIdx.x;
    if (e < N_EDGES) {
        int s = src[e];
        int ofs = atomicAdd(&cur[s], 1);
        esp[row_ptr[s] + ofs] = (dst[e] << 6) | (s & 63);
    }
}

__global__ void find_first(const int* __restrict__ batch, int* __restrict__ fidx) {
    int i = blockIdx.x * blockDim.x + threadIdx.x;
    if (i < N_NODES) {
        int b = batch[i];
        if (i == 0 || batch[i - 1] != b) fidx[b] = i;
    }
}

// ---------------- push phase: coalesced row read + fire-and-forget scatter atomics ----

__global__ __launch_bounds__(256, 8) void sage_push(
    const float* __restrict__ hin, const int* __restrict__ row_ptr,
    const int* __restrict__ esp, float* __restrict__ agg)
{
    __shared__ float Rs[TM * SA];     // this block's 64 src rows

    const int tid  = threadIdx.x;
    const int base = blockIdx.x * TM;
    const int lane = tid & 63;
    const int w    = tid >> 6;

    for (int idx = tid; idx < TM * D; idx += 256) {
        int m = idx >> 6, k = idx & 63;
        Rs[m * SA + k] = hin[(base << 6) + idx];   // coalesced stream
    }
    __syncthreads();

    const int e0    = row_ptr[base];
    const int e1    = row_ptr[base + TM];
    const int chunk = ((e1 - e0) + 3) >> 2;
    int e = e0 + w * chunk;
    const int ee = min(e + chunk, e1);

    for (; e + 64 <= ee; e += 64) {
        int pv = esp[e + lane];                    // 64 edges, one coalesced load
        #pragma unroll
        for (int u = 0; u < 64; ++u) {
            int p = __shfl(pv, u);                 // broadcast edge u
            float v = Rs[(p & 63) * SA + lane];    // LDS row read, 2-way alias
            atomicAdd(&agg[(p & 0x7fffffc0) + lane], v);  // fire-and-forget f32 atomic
        }
    }
    for (; e < ee; ++e) {
        int p = esp[e];
        atomicAdd(&agg[(p & 0x7fffffc0) + lane], Rs[(p & 63) * SA + lane]);
    }
}

// ---------------- finish: scale by in-degree + dual fp32 GEMM + re-zero agg ----------

__global__ __launch_bounds__(256, 4) void sage_finish(
    const float* __restrict__ hin, float* __restrict__ agg,
    const int* __restrict__ indeg, float* __restrict__ hout,
    const float* __restrict__ Wl, const float* __restrict__ bl,
    const float* __restrict__ Wr, int relu)
{
    __shared__ float As[TM * SA];
    __shared__ float Xs[TM * SA];
    __shared__ float invs[TM];

    const int tid  = threadIdx.x;
    const int base = blockIdx.x * TM;

    if (tid < TM) invs[tid] = 1.0f / (float)max(indeg[base + tid], 1);
    for (int idx = tid; idx < TM * D; idx += 256) {
        int m = idx >> 6, k = idx & 63;
        As[m * SA + k] = agg[(base << 6) + idx];
        Xs[m * SA + k] = hin[(base << 6) + idx];
        agg[(base << 6) + idx] = 0.0f;             // re-zero for the next push phase
    }
    __syncthreads();

    for (int idx = tid; idx < TM * D; idx += 256) {
        int m = idx >> 6, k = idx & 63;
        As[m * SA + k] *= invs[m];
    }
    __syncthreads();

    const int j0 = (tid & 15) << 2;
    const int m0 = (tid >> 4) << 2;
    float o[4][4];
    float4 b4 = *(const float4*)&bl[j0];
    #pragma unroll
    for (int mi = 0; mi < 4; ++mi) {
        o[mi][0] = b4.x; o[mi][1] = b4.y; o[mi][2] = b4.z; o[mi][3] = b4.w;
    }

    #pragma unroll 8
    for (int k = 0; k < D; ++k) {
        float4 wl = *(const float4*)&Wl[(k << 6) + j0];   // global, L1-resident broadcast
        float4 wr = *(const float4*)&Wr[(k << 6) + j0];
        #pragma unroll
        for (int mi = 0; mi < 4; ++mi) {
            float a = As[(m0 + mi) * SA + k];
            float x = Xs[(m0 + mi) * SA + k];
            o[mi][0] += a * wl.x + x * wr.x;
            o[mi][1] += a * wl.y + x * wr.y;
            o[mi][2] += a * wl.z + x * wr.z;
            o[mi][3] += a * wl.w + x * wr.w;
        }
    }

    #pragma unroll
    for (int mi = 0; mi < 4; ++mi) {
        float4 r = make_float4(o[mi][0], o[mi][1], o[mi][2], o[mi][3]);
        if (relu) {
            r.x = fmaxf(r.x, 0.f); r.y = fmaxf(r.y, 0.f);
            r.z = fmaxf(r.z, 0.f); r.w = fmaxf(r.w, 0.f);
        }
        *(float4*)&hout[(base + m0 + mi) * D + j0] = r;
    }
}

// ---------------- final layer GEMM on the 256 selected nodes ----------------

__global__ __launch_bounds__(256, 3) void final_gemm_sel(
    const float* __restrict__ hin, const float* __restrict__ agg,
    const int* __restrict__ indeg, const int* __restrict__ fidx,
    const float* __restrict__ Wl, const float* __restrict__ bl,
    const float* __restrict__ Wr, float* __restrict__ out)
{
    __shared__ float As[TM * SA];
    __shared__ float Xs[TM * SA];
    __shared__ int   nid[TM];
    __shared__ float invs[TM];

    const int tid  = threadIdx.x;
    const int base = blockIdx.x * TM;

    if (tid < TM) {
        int n = fidx[base + tid];
        nid[tid]  = n;
        invs[tid] = 1.0f / (float)max(indeg[n], 1);
    }
    __syncthreads();
    for (int idx = tid; idx < TM * D; idx += 256) {
        int m = idx >> 6, k = idx & 63;
        int n = nid[m];
        As[m * SA + k] = agg[n * D + k] * invs[m];
        Xs[m * SA + k] = hin[n * D + k];
    }
    __syncthreads();

    const int j0 = (tid & 15) << 2;
    const int m0 = (tid >> 4) << 2;
    float o[4][4];
    float4 b4 = *(const float4*)&bl[j0];
    #pragma unroll
    for (int mi = 0; mi < 4; ++mi) {
        o[mi][0] = b4.x; o[mi][1] = b4.y; o[mi][2] = b4.z; o[mi][3] = b4.w;
    }
    #pragma unroll 8
    for (int k = 0; k < D; ++k) {
        float4 wl = *(const float4*)&Wl[(k << 6) + j0];
        float4 wr = *(const float4*)&Wr[(k << 6) + j0];
        #pragma unroll
        for (int mi = 0; mi < 4; ++mi) {
            float a = As[(m0 + mi) * SA + k];
            float x = Xs[(m0 + mi) * SA + k];
            o[mi][0] += a * wl.x + x * wr.x;
            o[mi][1] += a * wl.y + x * wr.y;
            o[mi][2] += a * wl.z + x * wr.z;
            o[mi][3] += a * wl.w + x * wr.w;
        }
    }
    #pragma unroll
    for (int mi = 0; mi < 4; ++mi) {
        float4 r = make_float4(o[mi][0], o[mi][1], o[mi][2], o[mi][3]);
        *(float4*)&out[(base + m0 + mi) * D + j0] = r;
    }
}

// ---------------- launch ----------------

extern "C" void kernel_launch(void* const* d_in, const int* in_sizes, int n_in,
                              void* d_out, int out_size, void* d_ws, size_t ws_size,
                              hipStream_t stream)
{
    const float* x     = (const float*)d_in[0];
    const int*   ei    = (const int*)d_in[1];
    const int*   batch = (const int*)d_in[2];
    const float* Wl0 = (const float*)d_in[3];
    const float* bl0 = (const float*)d_in[4];
    const float* Wr0 = (const float*)d_in[5];
    const float* Wl1 = (const float*)d_in[6];
    const float* bl1 = (const float*)d_in[7];
    const float* Wr1 = (const float*)d_in[8];
    const float* Wl2 = (const float*)d_in[9];
    const float* bl2 = (const float*)d_in[10];
    const float* Wr2 = (const float*)d_in[11];
    float* out = (float*)d_out;

    const int* src = ei;             // edge_index[0]
    const int* dst = ei + N_EDGES;   // edge_index[1]

    char* ws = (char*)d_ws;
    size_t off = 0;
    auto alloc = [&](size_t bytes) -> void* {
        void* p = ws + off;
        off = (off + bytes + 255) & ~(size_t)255;
        return p;
    };
    int*   row_ptr = (int*)alloc((N_NODES + 1) * sizeof(int));   // CSR by src
    int*   cnt     = (int*)alloc(N_NODES * sizeof(int));         // out-degree, then cursor
    int*   indeg   = (int*)alloc(N_NODES * sizeof(int));         // in-degree (mean divisor)
    int*   bsums   = (int*)alloc(512 * sizeof(int));
    int*   fidx    = (int*)alloc(NG * sizeof(int));
    int*   esp     = (int*)alloc((size_t)N_EDGES * sizeof(int));
    float* agg     = (float*)alloc((size_t)N_NODES * D * sizeof(float));
    float* h1      = (float*)alloc((size_t)N_NODES * D * sizeof(float));
    float* h2      = (float*)alloc((size_t)N_NODES * D * sizeof(float));
    (void)ws_size; (void)in_sizes; (void)n_in; (void)out_size;

    // CSR by src + in-degree + agg zero
    zero_f4   <<<(N_NODES * D / 4 + 255) / 256, 256, 0, stream>>>((float4*)agg, N_NODES * D / 4);
    zero_ints <<<(N_NODES + 255) / 256, 256, 0, stream>>>(cnt, N_NODES);
    zero_ints <<<(N_NODES + 255) / 256, 256, 0, stream>>>(indeg, N_NODES);
    count_at  <<<(N_EDGES + 255) / 256, 256, 0, stream>>>(src, cnt);
    count_at  <<<(N_EDGES + 255) / 256, 256, 0, stream>>>(dst, indeg);
    scan_block<<<320, 256, 0, stream>>>(cnt, row_ptr, bsums);
    scan_top  <<<1, 512, 0, stream>>>(bsums);
    add_offsets<<<320, 256, 0, stream>>>(row_ptr, bsums);
    zero_ints <<<(N_NODES + 255) / 256, 256, 0, stream>>>(cnt, N_NODES);
    bucket_src<<<(N_EDGES + 255) / 256, 256, 0, stream>>>(src, dst, row_ptr, cnt, esp);
    find_first<<<320, 256, 0, stream>>>(batch, fidx);

    // layer 0
    sage_push  <<<N_NODES / TM, 256, 0, stream>>>(x, row_ptr, esp, agg);
    sage_finish<<<N_NODES / TM, 256, 0, stream>>>(x, agg, indeg, h1, Wl0, bl0, Wr0, 1);
    // layer 1
    sage_push  <<<N_NODES / TM, 256, 0, stream>>>(h1, row_ptr, esp, agg);
    sage_finish<<<N_NODES / TM, 256, 0, stream>>>(h1, agg, indeg, h2, Wl1, bl1, Wr1, 1);
    // layer 2 (only 256 nodes consumed)
    sage_push  <<<N_NODES / TM, 256, 0, stream>>>(h2, row_ptr, esp, agg);
    final_gemm_sel<<<NG / TM, 256, 0, stream>>>(h2, agg, indeg, fidx, Wl2, bl2, Wr2, out);
}

// Round 5
// 594.537 us; speedup vs baseline: 2.0849x; 2.0849x over previous
//
#include <hip/hip_runtime.h>

#define N_NODES 81920
#define N_EDGES 1310720
#define NG 256
#define D 64
#define TM 64
#define SA 65   // LDS row stride: bank=(row+lane)%32 -> uniform 2-way alias (free)

// ---------------- small utility kernels ----------------

__global__ void zero_ints(int* __restrict__ p, int n) {
    int i = blockIdx.x * blockDim.x + threadIdx.x;
    if (i < n) p[i] = 0;
}

__global__ void zero_f4(float4* __restrict__ p, int n4) {
    int i = blockIdx.x * blockDim.x + threadIdx.x;
    if (i < n4) p[i] = make_float4(0.f, 0.f, 0.f, 0.f);
}

__global__ void find_first(const int* __restrict__ batch, int* __restrict__ fidx) {
    int i = blockIdx.x * blockDim.x + threadIdx.x;
    if (i < N_NODES) {
        int b = batch[i];
        if (i == 0 || batch[i - 1] != b) fidx[b] = i;
    }
}

__global__ void mark_set(const int* __restrict__ fidx, int* __restrict__ m2,
                         int* __restrict__ m1) {
    int t = threadIdx.x;              // 1 block x 256
    int n = fidx[t];
    m2[n] = 1;
    m1[n] = 1;
}

// mark srcs of edges whose dst is in mdst
__global__ void mark_srcs(const int* __restrict__ src, const int* __restrict__ dst,
                          const int* __restrict__ mdst, int* __restrict__ msrc) {
    int e = blockIdx.x * blockDim.x + threadIdx.x;
    if (e < N_EDGES && mdst[dst[e]]) msrc[src[e]] = 1;   // idempotent plain store
}

__global__ void mask_or(int* __restrict__ a, const int* __restrict__ b) {
    int i = blockIdx.x * blockDim.x + threadIdx.x;
    a[i] |= b[i];
}

// wave-aggregated compaction of mask -> node list (order irrelevant)
__global__ void compact_list(const int* __restrict__ m, int* __restrict__ list,
                             int* __restrict__ count) {
    int i = blockIdx.x * blockDim.x + threadIdx.x;   // grid covers exactly N_NODES
    bool p = m[i] != 0;
    unsigned long long bm = __ballot(p);
    int lane = threadIdx.x & 63;
    int lt = __popcll(bm & ((1ull << lane) - 1));
    int base = 0;
    if (lane == 0 && bm) base = atomicAdd(count, __popcll(bm));
    base = __shfl(base, 0);
    if (p) list[base + lt] = i;
}

// in-degree of masked dsts (exact mean divisor for every needed node)
__global__ void count_dst_masked(const int* __restrict__ dst, const int* __restrict__ mdst,
                                 int* __restrict__ indeg) {
    int e = blockIdx.x * blockDim.x + threadIdx.x;
    if (e < N_EDGES) {
        int d = dst[e];
        if (mdst[d]) atomicAdd(&indeg[d], 1);
    }
}

// per-src count of edges whose dst is masked
__global__ void count_src_masked(const int* __restrict__ src, const int* __restrict__ dst,
                                 const int* __restrict__ mdst, int* __restrict__ cnt) {
    int e = blockIdx.x * blockDim.x + threadIdx.x;
    if (e < N_EDGES && mdst[dst[e]]) atomicAdd(&cnt[src[e]], 1);
}

__global__ void scan_block(const int* __restrict__ cnt, int* __restrict__ row_ptr,
                           int* __restrict__ bsums) {
    __shared__ int s[256];
    int tid = threadIdx.x;
    int i = blockIdx.x * 256 + tid;
    int v = cnt[i];
    s[tid] = v;
    __syncthreads();
    for (int ofs = 1; ofs < 256; ofs <<= 1) {
        int t = (tid >= ofs) ? s[tid - ofs] : 0;
        __syncthreads();
        s[tid] += t;
        __syncthreads();
    }
    row_ptr[i] = s[tid] - v;               // exclusive
    if (tid == 255) bsums[blockIdx.x] = s[255];
}

__global__ void scan_top(int* __restrict__ bsums) {   // 320 entries, 1 block x 512
    __shared__ int s[512];
    int tid = threadIdx.x;
    int v = (tid < 320) ? bsums[tid] : 0;
    s[tid] = v;
    __syncthreads();
    for (int ofs = 1; ofs < 512; ofs <<= 1) {
        int t = (tid >= ofs) ? s[tid - ofs] : 0;
        __syncthreads();
        s[tid] += t;
        __syncthreads();
    }
    if (tid < 320) bsums[tid] = s[tid] - v; // exclusive
}

__global__ void add_offsets(int* __restrict__ row_ptr, const int* __restrict__ bsums,
                            const int* __restrict__ cnt) {
    int i = blockIdx.x * 256 + threadIdx.x;
    int v = row_ptr[i] + bsums[blockIdx.x];
    row_ptr[i] = v;
    if (i == N_NODES - 1) row_ptr[N_NODES] = v + cnt[i];
}

// masked CSR-by-src bucket; pack (dst<<6)|(src&63)
__global__ void bucket_masked(const int* __restrict__ src, const int* __restrict__ dst,
                              const int* __restrict__ mdst, const int* __restrict__ row_ptr,
                              int* __restrict__ cur, int* __restrict__ esp) {
    int e = blockIdx.x * blockDim.x + threadIdx.x;
    if (e < N_EDGES) {
        int d = dst[e];
        if (mdst[d]) {
            int s = src[e];
            int ofs = atomicAdd(&cur[s], 1);
            esp[row_ptr[s] + ofs] = (d << 6) | (s & 63);
        }
    }
}

// ---------------- push phase: LDS-staged rows + fire-and-forget scatter atomics ----

__global__ __launch_bounds__(256, 8) void sage_push(
    const float* __restrict__ hin, const int* __restrict__ row_ptr,
    const int* __restrict__ esp, float* __restrict__ agg)
{
    __shared__ float Rs[TM * SA];     // this block's 64 src rows

    const int tid  = threadIdx.x;
    const int base = blockIdx.x * TM;
    const int lane = tid & 63;
    const int w    = tid >> 6;

    for (int idx = tid; idx < TM * D; idx += 256) {
        int m = idx >> 6, k = idx & 63;
        Rs[m * SA + k] = hin[(base << 6) + idx];   // coalesced stream
    }
    __syncthreads();

    const int e0    = row_ptr[base];
    const int e1    = row_ptr[base + TM];
    const int chunk = ((e1 - e0) + 3) >> 2;
    int e = e0 + w * chunk;
    const int ee = min(e + chunk, e1);

    for (; e + 64 <= ee; e += 64) {
        int pv = esp[e + lane];                    // 64 edges, one coalesced load
        #pragma unroll
        for (int u = 0; u < 64; ++u) {
            int p = __shfl(pv, u);                 // broadcast edge u
            float v = Rs[(p & 63) * SA + lane];    // LDS row read, 2-way alias
            atomicAdd(&agg[(p & 0x7fffffc0) + lane], v);  // fire-and-forget f32 atomic
        }
    }
    for (; e < ee; ++e) {
        int p = esp[e];
        atomicAdd(&agg[(p & 0x7fffffc0) + lane], Rs[(p & 63) * SA + lane]);
    }
}

// ---------------- finish (all nodes): scale + dual fp32 GEMM + re-zero agg ----------

__global__ __launch_bounds__(256, 4) void sage_finish(
    const float* __restrict__ hin, float* __restrict__ agg,
    const int* __restrict__ indeg, float* __restrict__ hout,
    const float* __restrict__ Wl, const float* __restrict__ bl,
    const float* __restrict__ Wr, int relu)
{
    __shared__ float As[TM * SA];
    __shared__ float Xs[TM * SA];
    __shared__ float invs[TM];

    const int tid  = threadIdx.x;
    const int base = blockIdx.x * TM;

    if (tid < TM) invs[tid] = 1.0f / (float)max(indeg[base + tid], 1);
    for (int idx = tid; idx < TM * D; idx += 256) {
        int m = idx >> 6, k = idx & 63;
        As[m * SA + k] = agg[(base << 6) + idx];
        Xs[m * SA + k] = hin[(base << 6) + idx];
        agg[(base << 6) + idx] = 0.0f;             // re-zero for the next push phase
    }
    __syncthreads();

    for (int idx = tid; idx < TM * D; idx += 256) {
        int m = idx >> 6, k = idx & 63;
        As[m * SA + k] *= invs[m];
    }
    __syncthreads();

    const int j0 = (tid & 15) << 2;
    const int m0 = (tid >> 4) << 2;
    float o[4][4];
    float4 b4 = *(const float4*)&bl[j0];
    #pragma unroll
    for (int mi = 0; mi < 4; ++mi) {
        o[mi][0] = b4.x; o[mi][1] = b4.y; o[mi][2] = b4.z; o[mi][3] = b4.w;
    }

    #pragma unroll 8
    for (int k = 0; k < D; ++k) {
        float4 wl = *(const float4*)&Wl[(k << 6) + j0];
        float4 wr = *(const float4*)&Wr[(k << 6) + j0];
        #pragma unroll
        for (int mi = 0; mi < 4; ++mi) {
            float a = As[(m0 + mi) * SA + k];
            float x = Xs[(m0 + mi) * SA + k];
            o[mi][0] += a * wl.x + x * wr.x;
            o[mi][1] += a * wl.y + x * wr.y;
            o[mi][2] += a * wl.z + x * wr.z;
            o[mi][3] += a * wl.w + x * wr.w;
        }
    }

    #pragma unroll
    for (int mi = 0; mi < 4; ++mi) {
        float4 r = make_float4(o[mi][0], o[mi][1], o[mi][2], o[mi][3]);
        if (relu) {
            r.x = fmaxf(r.x, 0.f); r.y = fmaxf(r.y, 0.f);
            r.z = fmaxf(r.z, 0.f); r.w = fmaxf(r.w, 0.f);
        }
        *(float4*)&hout[(base + m0 + mi) * D + j0] = r;
    }
}

// ---------------- finish on a compacted node list (layer 1: ~4.3K nodes) ----------

__global__ __launch_bounds__(256, 4) void sage_finish_sel(
    const float* __restrict__ hin, float* __restrict__ agg,
    const int* __restrict__ indeg, const int* __restrict__ list,
    const int* __restrict__ pcount, float* __restrict__ hout,
    const float* __restrict__ Wl, const float* __restrict__ bl,
    const float* __restrict__ Wr, int relu)
{
    __shared__ float As[TM * SA];
    __shared__ float Xs[TM * SA];
    __shared__ float invs[TM];
    __shared__ int   nid[TM];

    const int cntv = *pcount;
    const int base = blockIdx.x * TM;
    if (base >= cntv) return;

    const int tid = threadIdx.x;
    if (tid < TM) {
        int n = (base + tid < cntv) ? list[base + tid] : -1;
        nid[tid]  = n;
        invs[tid] = (n >= 0) ? 1.0f / (float)max(indeg[n], 1) : 0.f;
    }
    __syncthreads();
    for (int idx = tid; idx < TM * D; idx += 256) {
        int m = idx >> 6, k = idx & 63;
        int n = nid[m];
        if (n >= 0) {
            As[m * SA + k] = agg[n * D + k] * invs[m];
            Xs[m * SA + k] = hin[n * D + k];
            agg[n * D + k] = 0.0f;                 // re-zero for layer-2 push
        } else {
            As[m * SA + k] = 0.f;
            Xs[m * SA + k] = 0.f;
        }
    }
    __syncthreads();

    const int j0 = (tid & 15) << 2;
    const int m0 = (tid >> 4) << 2;
    float o[4][4];
    float4 b4 = *(const float4*)&bl[j0];
    #pragma unroll
    for (int mi = 0; mi < 4; ++mi) {
        o[mi][0] = b4.x; o[mi][1] = b4.y; o[mi][2] = b4.z; o[mi][3] = b4.w;
    }
    #pragma unroll 8
    for (int k = 0; k < D; ++k) {
        float4 wl = *(const float4*)&Wl[(k << 6) + j0];
        float4 wr = *(const float4*)&Wr[(k << 6) + j0];
        #pragma unroll
        for (int mi = 0; mi < 4; ++mi) {
            float a = As[(m0 + mi) * SA + k];
            float x = Xs[(m0 + mi) * SA + k];
            o[mi][0] += a * wl.x + x * wr.x;
            o[mi][1] += a * wl.y + x * wr.y;
            o[mi][2] += a * wl.z + x * wr.z;
            o[mi][3] += a * wl.w + x * wr.w;
        }
    }
    #pragma unroll
    for (int mi = 0; mi < 4; ++mi) {
        int n = nid[m0 + mi];
        if (n >= 0) {
            float4 r = make_float4(o[mi][0], o[mi][1], o[mi][2], o[mi][3]);
            if (relu) {
                r.x = fmaxf(r.x, 0.f); r.y = fmaxf(r.y, 0.f);
                r.z = fmaxf(r.z, 0.f); r.w = fmaxf(r.w, 0.f);
            }
            *(float4*)&hout[n * D + j0] = r;
        }
    }
}

// ---------------- final layer GEMM on the 256 selected nodes ----------------

__global__ __launch_bounds__(256, 3) void final_gemm_sel(
    const float* __restrict__ hin, const float* __restrict__ agg,
    const int* __restrict__ indeg, const int* __restrict__ fidx,
    const float* __restrict__ Wl, const float* __restrict__ bl,
    const float* __restrict__ Wr, float* __restrict__ out)
{
    __shared__ float As[TM * SA];
    __shared__ float Xs[TM * SA];
    __shared__ int   nid[TM];
    __shared__ float invs[TM];

    const int tid  = threadIdx.x;
    const int base = blockIdx.x * TM;

    if (tid < TM) {
        int n = fidx[base + tid];
        nid[tid]  = n;
        invs[tid] = 1.0f / (float)max(indeg[n], 1);
    }
    __syncthreads();
    for (int idx = tid; idx < TM * D; idx += 256) {
        int m = idx >> 6, k = idx & 63;
        int n = nid[m];
        As[m * SA + k] = agg[n * D + k] * invs[m];
        Xs[m * SA + k] = hin[n * D + k];
    }
    __syncthreads();

    const int j0 = (tid & 15) << 2;
    const int m0 = (tid >> 4) << 2;
    float o[4][4];
    float4 b4 = *(const float4*)&bl[j0];
    #pragma unroll
    for (int mi = 0; mi < 4; ++mi) {
        o[mi][0] = b4.x; o[mi][1] = b4.y; o[mi][2] = b4.z; o[mi][3] = b4.w;
    }
    #pragma unroll 8
    for (int k = 0; k < D; ++k) {
        float4 wl = *(const float4*)&Wl[(k << 6) + j0];
        float4 wr = *(const float4*)&Wr[(k << 6) + j0];
        #pragma unroll
        for (int mi = 0; mi < 4; ++mi) {
            float a = As[(m0 + mi) * SA + k];
            float x = Xs[(m0 + mi) * SA + k];
            o[mi][0] += a * wl.x + x * wr.x;
            o[mi][1] += a * wl.y + x * wr.y;
            o[mi][2] += a * wl.z + x * wr.z;
            o[mi][3] += a * wl.w + x * wr.w;
        }
    }
    #pragma unroll
    for (int mi = 0; mi < 4; ++mi) {
        float4 r = make_float4(o[mi][0], o[mi][1], o[mi][2], o[mi][3]);
        *(float4*)&out[(base + m0 + mi) * D + j0] = r;
    }
}

// ---------------- launch ----------------

extern "C" void kernel_launch(void* const* d_in, const int* in_sizes, int n_in,
                              void* d_out, int out_size, void* d_ws, size_t ws_size,
                              hipStream_t stream)
{
    const float* x     = (const float*)d_in[0];
    const int*   ei    = (const int*)d_in[1];
    const int*   batch = (const int*)d_in[2];
    const float* Wl0 = (const float*)d_in[3];
    const float* bl0 = (const float*)d_in[4];
    const float* Wr0 = (const float*)d_in[5];
    const float* Wl1 = (const float*)d_in[6];
    const float* bl1 = (const float*)d_in[7];
    const float* Wr1 = (const float*)d_in[8];
    const float* Wl2 = (const float*)d_in[9];
    const float* bl2 = (const float*)d_in[10];
    const float* Wr2 = (const float*)d_in[11];
    float* out = (float*)d_out;

    const int* src = ei;             // edge_index[0]
    const int* dst = ei + N_EDGES;   // edge_index[1]

    char* ws = (char*)d_ws;
    size_t off = 0;
    auto alloc = [&](size_t bytes) -> void* {
        void* p = ws + off;
        off = (off + bytes + 255) & ~(size_t)255;
        return p;
    };
    int*   row_ptr = (int*)alloc((N_NODES + 1) * sizeof(int));   // reused per layer
    int*   bsums   = (int*)alloc(512 * sizeof(int));
    int*   fidx    = (int*)alloc(NG * sizeof(int));
    int*   list1   = (int*)alloc(N_NODES * sizeof(int));
    int*   esp     = (int*)alloc((size_t)N_EDGES * sizeof(int)); // reused per layer
    float* agg     = (float*)alloc((size_t)N_NODES * D * sizeof(float));
    float* h1      = (float*)alloc((size_t)N_NODES * D * sizeof(float));
    float* h2      = (float*)alloc((size_t)N_NODES * D * sizeof(float));
    // contiguous zeroable int region: indeg,m0,m1,m2,cnt0,cnt1,cnt2,cur0,cur1,cur2,nS1
    int*   zbase   = (int*)alloc((size_t)(10 * N_NODES + 64) * sizeof(int));
    int* indeg = zbase;
    int* m0    = zbase + 1 * N_NODES;
    int* m1    = zbase + 2 * N_NODES;
    int* m2    = zbase + 3 * N_NODES;
    int* cnt0  = zbase + 4 * N_NODES;
    int* cnt1  = zbase + 5 * N_NODES;
    int* cnt2  = zbase + 6 * N_NODES;
    int* cur0  = zbase + 7 * N_NODES;
    int* cur1  = zbase + 8 * N_NODES;
    int* cur2  = zbase + 9 * N_NODES;
    int* nS1   = zbase + 10 * N_NODES;
    (void)ws_size; (void)in_sizes; (void)n_in; (void)out_size;

    const int EB = (N_EDGES + 255) / 256;   // 5120
    const int NB = N_NODES / 256;           // 320

    zero_f4  <<<(N_NODES * D / 4 + 255) / 256, 256, 0, stream>>>((float4*)agg, N_NODES * D / 4);
    zero_ints<<<(10 * N_NODES + 64 + 255) / 256, 256, 0, stream>>>(zbase, 10 * N_NODES + 64);
    find_first<<<NB, 256, 0, stream>>>(batch, fidx);

    // masks: m2 = outputs; m1 = m2 ∪ src(dst∈m2); m0 = m1 ∪ src(dst∈m1)
    mark_set <<<1, NG, 0, stream>>>(fidx, m2, m1);
    mark_srcs<<<EB, 256, 0, stream>>>(src, dst, m2, m1);
    mark_srcs<<<EB, 256, 0, stream>>>(src, dst, m1, m0);
    mask_or  <<<NB, 256, 0, stream>>>(m0, m1);
    compact_list<<<NB, 256, 0, stream>>>(m1, list1, nS1);
    count_dst_masked<<<EB, 256, 0, stream>>>(dst, m0, indeg);

    // ---- layer 0: edges with dst ∈ m0 (~57%) ----
    count_src_masked<<<EB, 256, 0, stream>>>(src, dst, m0, cnt0);
    scan_block<<<NB, 256, 0, stream>>>(cnt0, row_ptr, bsums);
    scan_top  <<<1, 512, 0, stream>>>(bsums);
    add_offsets<<<NB, 256, 0, stream>>>(row_ptr, bsums, cnt0);
    bucket_masked<<<EB, 256, 0, stream>>>(src, dst, m0, row_ptr, cur0, esp);
    sage_push  <<<N_NODES / TM, 256, 0, stream>>>(x, row_ptr, esp, agg);
    sage_finish<<<N_NODES / TM, 256, 0, stream>>>(x, agg, indeg, h1, Wl0, bl0, Wr0, 1);

    // ---- layer 1: edges with dst ∈ m1 (~69K) ----
    count_src_masked<<<EB, 256, 0, stream>>>(src, dst, m1, cnt1);
    scan_block<<<NB, 256, 0, stream>>>(cnt1, row_ptr, bsums);
    scan_top  <<<1, 512, 0, stream>>>(bsums);
    add_offsets<<<NB, 256, 0, stream>>>(row_ptr, bsums, cnt1);
    bucket_masked<<<EB, 256, 0, stream>>>(src, dst, m1, row_ptr, cur1, esp);
    sage_push  <<<N_NODES / TM, 256, 0, stream>>>(h1, row_ptr, esp, agg);
    sage_finish_sel<<<N_NODES / TM, 256, 0, stream>>>(h1, agg, indeg, list1, nS1,
                                                      h2, Wl1, bl1, Wr1, 1);

    // ---- layer 2: edges with dst ∈ m2 (~5K) ----
    count_src_masked<<<EB, 256, 0, stream>>>(src, dst, m2, cnt2);
    scan_block<<<NB, 256, 0, stream>>>(cnt2, row_ptr, bsums);
    scan_top  <<<1, 512, 0, stream>>>(bsums);
    add_offsets<<<NB, 256, 0, stream>>>(row_ptr, bsums, cnt2);
    bucket_masked<<<EB, 256, 0, stream>>>(src, dst, m2, row_ptr, cur2, esp);
    sage_push  <<<N_NODES / TM, 256, 0, stream>>>(h2, row_ptr, esp, agg);
    final_gemm_sel<<<NG / TM, 256, 0, stream>>>(h2, agg, indeg, fidx, Wl2, bl2, Wr2, out);
}

// Round 6
// 550.070 us; speedup vs baseline: 2.2534x; 1.0808x over previous
//
#include <hip/hip_runtime.h>

#define N_NODES 81920
#define N_EDGES 1310720
#define NG 256
#define D 64
#define TM 64
#define SA 65       // LDS row stride: bank=(row+lane)%32 -> uniform 2-way alias (free)
#define NB 320      // node blocks of 256
#define RPSTR (N_NODES + 64)

// ---------------- small utility kernels ----------------

__global__ void zero_ints(int* __restrict__ p, int n) {
    int i = blockIdx.x * blockDim.x + threadIdx.x;
    if (i < n) p[i] = 0;
}

__global__ void zero_f4(float4* __restrict__ p, int n4) {
    int i = blockIdx.x * blockDim.x + threadIdx.x;
    if (i < n4) p[i] = make_float4(0.f, 0.f, 0.f, 0.f);
}

__global__ void find_first(const int* __restrict__ batch, int* __restrict__ fidx) {
    int i = blockIdx.x * blockDim.x + threadIdx.x;
    if (i < N_NODES) {
        int b = batch[i];
        if (i == 0 || batch[i - 1] != b) fidx[b] = i;
    }
}

__global__ void mark_set(const int* __restrict__ fidx, int* __restrict__ m2,
                         int* __restrict__ m1) {
    int t = threadIdx.x;              // 1 block x 256
    int n = fidx[t];
    m2[n] = 1;
    m1[n] = 1;
}

// mark srcs of edges whose dst is in mdst
__global__ void mark_srcs(const int* __restrict__ src, const int* __restrict__ dst,
                          const int* __restrict__ mdst, int* __restrict__ msrc) {
    int e = blockIdx.x * blockDim.x + threadIdx.x;
    if (e < N_EDGES && mdst[dst[e]]) msrc[src[e]] = 1;   // idempotent plain store
}

__global__ void mask_or(int* __restrict__ a, const int* __restrict__ b) {
    int i = blockIdx.x * blockDim.x + threadIdx.x;
    a[i] |= b[i];
}

// compact two masks -> two node lists (order irrelevant)
__global__ void compact2(const int* __restrict__ m0, const int* __restrict__ m1,
                         int* __restrict__ list0, int* __restrict__ list1,
                         int* __restrict__ n0, int* __restrict__ n1) {
    int i = blockIdx.x * 256 + threadIdx.x;
    int lane = threadIdx.x & 63;
    bool p0 = m0[i] != 0;
    bool p1 = m1[i] != 0;
    unsigned long long b0 = __ballot(p0);
    int lt = __popcll(b0 & ((1ull << lane) - 1));
    int base = 0;
    if (lane == 0 && b0) base = atomicAdd(n0, __popcll(b0));
    base = __shfl(base, 0);
    if (p0) list0[base + lt] = i;
    unsigned long long b1 = __ballot(p1);
    lt = __popcll(b1 & ((1ull << lane) - 1));
    base = 0;
    if (lane == 0 && b1) base = atomicAdd(n1, __popcll(b1));
    base = __shfl(base, 0);
    if (p1) list1[base + lt] = i;
}

// ONE edge pass: indeg (m0 dsts) + per-src counts for all three layers (m2⊂m1⊂m0)
__global__ void fused_count(const int* __restrict__ src, const int* __restrict__ dst,
                            const int* __restrict__ m0, const int* __restrict__ m1,
                            const int* __restrict__ m2, int* __restrict__ indeg,
                            int* __restrict__ cnt0, int* __restrict__ cnt1,
                            int* __restrict__ cnt2) {
    int e = blockIdx.x * blockDim.x + threadIdx.x;
    if (e >= N_EDGES) return;
    int d = dst[e];
    if (!m0[d]) return;
    int s = src[e];
    atomicAdd(&indeg[d], 1);
    atomicAdd(&cnt0[s], 1);
    if (m1[d]) atomicAdd(&cnt1[s], 1);
    if (m2[d]) atomicAdd(&cnt2[s], 1);
}

// batched scans over cnt3 = [cnt0|cnt1|cnt2] (contiguous)
__global__ void scan_block3(const int* __restrict__ cnt3, int* __restrict__ rp3,
                            int* __restrict__ bsums3) {
    int a = blockIdx.x / NB, blk = blockIdx.x % NB;
    const int* cnt = cnt3 + a * N_NODES;
    int* rp = rp3 + a * RPSTR;
    __shared__ int s[256];
    int tid = threadIdx.x;
    int i = blk * 256 + tid;
    int v = cnt[i];
    s[tid] = v;
    __syncthreads();
    for (int ofs = 1; ofs < 256; ofs <<= 1) {
        int t = (tid >= ofs) ? s[tid - ofs] : 0;
        __syncthreads();
        s[tid] += t;
        __syncthreads();
    }
    rp[i] = s[tid] - v;                       // exclusive
    if (tid == 255) bsums3[a * NB + blk] = s[255];
}

__global__ void scan_top3(int* __restrict__ bsums3) {   // 3 blocks x 512
    int* bs = bsums3 + blockIdx.x * NB;
    __shared__ int s[512];
    int tid = threadIdx.x;
    int v = (tid < NB) ? bs[tid] : 0;
    s[tid] = v;
    __syncthreads();
    for (int ofs = 1; ofs < 512; ofs <<= 1) {
        int t = (tid >= ofs) ? s[tid - ofs] : 0;
        __syncthreads();
        s[tid] += t;
        __syncthreads();
    }
    if (tid < NB) bs[tid] = s[tid] - v;       // exclusive
}

__global__ void add_offsets3(int* __restrict__ rp3, const int* __restrict__ bsums3,
                             const int* __restrict__ cnt3) {
    int a = blockIdx.x / NB, blk = blockIdx.x % NB;
    int* rp = rp3 + a * RPSTR;
    int i = blk * 256 + threadIdx.x;
    int v = rp[i] + bsums3[a * NB + blk];
    rp[i] = v;
    if (i == N_NODES - 1) rp[N_NODES] = v + cnt3[a * N_NODES + i];
}

// ONE edge pass: bucket into all three CSR-by-src lists; pack (dst<<6)|(src&63)
__global__ void fused_bucket(const int* __restrict__ src, const int* __restrict__ dst,
                             const int* __restrict__ m0, const int* __restrict__ m1,
                             const int* __restrict__ m2, const int* __restrict__ rp3,
                             int* __restrict__ cur0, int* __restrict__ cur1,
                             int* __restrict__ cur2, int* __restrict__ esp0,
                             int* __restrict__ esp1, int* __restrict__ esp2) {
    int e = blockIdx.x * blockDim.x + threadIdx.x;
    if (e >= N_EDGES) return;
    int d = dst[e];
    if (!m0[d]) return;
    int s = src[e];
    int pk = (d << 6) | (s & 63);
    int o = atomicAdd(&cur0[s], 1);
    esp0[rp3[s] + o] = pk;
    if (m1[d]) {
        o = atomicAdd(&cur1[s], 1);
        esp1[rp3[RPSTR + s] + o] = pk;
    }
    if (m2[d]) {
        o = atomicAdd(&cur2[s], 1);
        esp2[rp3[2 * RPSTR + s] + o] = pk;
    }
}

// ---------------- push phase: LDS-staged rows + fire-and-forget scatter atomics ----

__global__ __launch_bounds__(256, 8) void sage_push(
    const float* __restrict__ hin, const int* __restrict__ row_ptr,
    const int* __restrict__ esp, float* __restrict__ agg)
{
    __shared__ float Rs[TM * SA];     // this block's 64 src rows

    const int tid  = threadIdx.x;
    const int base = blockIdx.x * TM;
    const int lane = tid & 63;
    const int w    = tid >> 6;

    const int e0 = row_ptr[base];
    const int e1 = row_ptr[base + TM];
    if (e0 == e1) return;             // nothing to push from this block

    for (int idx = tid; idx < TM * D; idx += 256) {
        int m = idx >> 6, k = idx & 63;
        Rs[m * SA + k] = hin[(base << 6) + idx];   // coalesced stream
    }
    __syncthreads();

    const int chunk = ((e1 - e0) + 3) >> 2;
    int e = e0 + w * chunk;
    const int ee = min(e + chunk, e1);

    for (; e + 64 <= ee; e += 64) {
        int pv = esp[e + lane];                    // 64 edges, one coalesced load
        #pragma unroll
        for (int u = 0; u < 64; ++u) {
            int p = __shfl(pv, u);                 // broadcast edge u
            float v = Rs[(p & 63) * SA + lane];    // LDS row read, 2-way alias
            atomicAdd(&agg[(p & 0x7fffffc0) + lane], v);  // fire-and-forget f32 atomic
        }
    }
    for (; e < ee; ++e) {
        int p = esp[e];
        atomicAdd(&agg[(p & 0x7fffffc0) + lane], Rs[(p & 63) * SA + lane]);
    }
}

// ---------------- finish on a compacted node list: scale + dual fp32 GEMM + re-zero ----

__global__ __launch_bounds__(256, 4) void sage_finish_sel(
    const float* __restrict__ hin, float* __restrict__ agg,
    const int* __restrict__ indeg, const int* __restrict__ list,
    const int* __restrict__ pcount, float* __restrict__ hout,
    const float* __restrict__ Wl, const float* __restrict__ bl,
    const float* __restrict__ Wr, int relu)
{
    __shared__ float As[TM * SA];
    __shared__ float Xs[TM * SA];
    __shared__ float invs[TM];
    __shared__ int   nid[TM];

    const int cntv = *pcount;
    const int base = blockIdx.x * TM;
    if (base >= cntv) return;

    const int tid = threadIdx.x;
    if (tid < TM) {
        int n = (base + tid < cntv) ? list[base + tid] : -1;
        nid[tid]  = n;
        invs[tid] = (n >= 0) ? 1.0f / (float)max(indeg[n], 1) : 0.f;
    }
    __syncthreads();
    for (int idx = tid; idx < TM * D; idx += 256) {
        int m = idx >> 6, k = idx & 63;
        int n = nid[m];
        if (n >= 0) {
            As[m * SA + k] = agg[n * D + k] * invs[m];
            Xs[m * SA + k] = hin[n * D + k];
            agg[n * D + k] = 0.0f;                 // re-zero for the next push phase
        } else {
            As[m * SA + k] = 0.f;
            Xs[m * SA + k] = 0.f;
        }
    }
    __syncthreads();

    const int j0 = (tid & 15) << 2;
    const int m0 = (tid >> 4) << 2;
    float o[4][4];
    float4 b4 = *(const float4*)&bl[j0];
    #pragma unroll
    for (int mi = 0; mi < 4; ++mi) {
        o[mi][0] = b4.x; o[mi][1] = b4.y; o[mi][2] = b4.z; o[mi][3] = b4.w;
    }
    #pragma unroll 8
    for (int k = 0; k < D; ++k) {
        float4 wl = *(const float4*)&Wl[(k << 6) + j0];   // global, L1-resident broadcast
        float4 wr = *(const float4*)&Wr[(k << 6) + j0];
        #pragma unroll
        for (int mi = 0; mi < 4; ++mi) {
            float a = As[(m0 + mi) * SA + k];
            float x = Xs[(m0 + mi) * SA + k];
            o[mi][0] += a * wl.x + x * wr.x;
            o[mi][1] += a * wl.y + x * wr.y;
            o[mi][2] += a * wl.z + x * wr.z;
            o[mi][3] += a * wl.w + x * wr.w;
        }
    }
    #pragma unroll
    for (int mi = 0; mi < 4; ++mi) {
        int n = nid[m0 + mi];
        if (n >= 0) {
            float4 r = make_float4(o[mi][0], o[mi][1], o[mi][2], o[mi][3]);
            if (relu) {
                r.x = fmaxf(r.x, 0.f); r.y = fmaxf(r.y, 0.f);
                r.z = fmaxf(r.z, 0.f); r.w = fmaxf(r.w, 0.f);
            }
            *(float4*)&hout[n * D + j0] = r;
        }
    }
}

// ---------------- final layer GEMM on the 256 selected nodes ----------------

__global__ __launch_bounds__(256, 3) void final_gemm_sel(
    const float* __restrict__ hin, const float* __restrict__ agg,
    const int* __restrict__ indeg, const int* __restrict__ fidx,
    const float* __restrict__ Wl, const float* __restrict__ bl,
    const float* __restrict__ Wr, float* __restrict__ out)
{
    __shared__ float As[TM * SA];
    __shared__ float Xs[TM * SA];
    __shared__ int   nid[TM];
    __shared__ float invs[TM];

    const int tid  = threadIdx.x;
    const int base = blockIdx.x * TM;

    if (tid < TM) {
        int n = fidx[base + tid];
        nid[tid]  = n;
        invs[tid] = 1.0f / (float)max(indeg[n], 1);
    }
    __syncthreads();
    for (int idx = tid; idx < TM * D; idx += 256) {
        int m = idx >> 6, k = idx & 63;
        int n = nid[m];
        As[m * SA + k] = agg[n * D + k] * invs[m];
        Xs[m * SA + k] = hin[n * D + k];
    }
    __syncthreads();

    const int j0 = (tid & 15) << 2;
    const int m0 = (tid >> 4) << 2;
    float o[4][4];
    float4 b4 = *(const float4*)&bl[j0];
    #pragma unroll
    for (int mi = 0; mi < 4; ++mi) {
        o[mi][0] = b4.x; o[mi][1] = b4.y; o[mi][2] = b4.z; o[mi][3] = b4.w;
    }
    #pragma unroll 8
    for (int k = 0; k < D; ++k) {
        float4 wl = *(const float4*)&Wl[(k << 6) + j0];
        float4 wr = *(const float4*)&Wr[(k << 6) + j0];
        #pragma unroll
        for (int mi = 0; mi < 4; ++mi) {
            float a = As[(m0 + mi) * SA + k];
            float x = Xs[(m0 + mi) * SA + k];
            o[mi][0] += a * wl.x + x * wr.x;
            o[mi][1] += a * wl.y + x * wr.y;
            o[mi][2] += a * wl.z + x * wr.z;
            o[mi][3] += a * wl.w + x * wr.w;
        }
    }
    #pragma unroll
    for (int mi = 0; mi < 4; ++mi) {
        float4 r = make_float4(o[mi][0], o[mi][1], o[mi][2], o[mi][3]);
        *(float4*)&out[(base + m0 + mi) * D + j0] = r;
    }
}

// ---------------- launch ----------------

extern "C" void kernel_launch(void* const* d_in, const int* in_sizes, int n_in,
                              void* d_out, int out_size, void* d_ws, size_t ws_size,
                              hipStream_t stream)
{
    const float* x     = (const float*)d_in[0];
    const int*   ei    = (const int*)d_in[1];
    const int*   batch = (const int*)d_in[2];
    const float* Wl0 = (const float*)d_in[3];
    const float* bl0 = (const float*)d_in[4];
    const float* Wr0 = (const float*)d_in[5];
    const float* Wl1 = (const float*)d_in[6];
    const float* bl1 = (const float*)d_in[7];
    const float* Wr1 = (const float*)d_in[8];
    const float* Wl2 = (const float*)d_in[9];
    const float* bl2 = (const float*)d_in[10];
    const float* Wr2 = (const float*)d_in[11];
    float* out = (float*)d_out;

    const int* src = ei;             // edge_index[0]
    const int* dst = ei + N_EDGES;   // edge_index[1]

    char* ws = (char*)d_ws;
    size_t off = 0;
    auto alloc = [&](size_t bytes) -> void* {
        void* p = ws + off;
        off = (off + bytes + 255) & ~(size_t)255;
        return p;
    };
    int*   rp3     = (int*)alloc((size_t)3 * RPSTR * sizeof(int));
    int*   bsums3  = (int*)alloc(3 * NB * sizeof(int));
    int*   fidx    = (int*)alloc(NG * sizeof(int));
    int*   list0   = (int*)alloc(N_NODES * sizeof(int));
    int*   list1   = (int*)alloc(N_NODES * sizeof(int));
    int*   esp0    = (int*)alloc((size_t)N_EDGES * sizeof(int));
    int*   esp1    = (int*)alloc((size_t)(N_EDGES / 4) * sizeof(int));   // ~69K expected
    int*   esp2    = (int*)alloc((size_t)(N_EDGES / 16) * sizeof(int));  // ~4K expected
    float* agg     = (float*)alloc((size_t)N_NODES * D * sizeof(float));
    float* h1      = (float*)alloc((size_t)N_NODES * D * sizeof(float));
    float* h2      = (float*)alloc((size_t)N_NODES * D * sizeof(float));
    // contiguous zeroable ints: indeg, m0, m1, m2, cnt0|cnt1|cnt2, cur0, cur1, cur2, n0, n1
    int*   zbase   = (int*)alloc((size_t)(10 * N_NODES + 64) * sizeof(int));
    int* indeg = zbase;
    int* m0    = zbase + 1 * N_NODES;
    int* m1    = zbase + 2 * N_NODES;
    int* m2    = zbase + 3 * N_NODES;
    int* cnt3  = zbase + 4 * N_NODES;          // cnt0,cnt1,cnt2 contiguous
    int* cur0  = zbase + 7 * N_NODES;
    int* cur1  = zbase + 8 * N_NODES;
    int* cur2  = zbase + 9 * N_NODES;
    int* n0    = zbase + 10 * N_NODES;
    int* n1    = zbase + 10 * N_NODES + 1;
    (void)ws_size; (void)in_sizes; (void)n_in; (void)out_size;

    const int EB = (N_EDGES + 255) / 256;   // 5120

    zero_f4  <<<(N_NODES * D / 4 + 255) / 256, 256, 0, stream>>>((float4*)agg, N_NODES * D / 4);
    zero_ints<<<(10 * N_NODES + 64 + 255) / 256, 256, 0, stream>>>(zbase, 10 * N_NODES + 64);
    find_first<<<NB, 256, 0, stream>>>(batch, fidx);

    // masks: m2 = outputs; m1 = m2 ∪ src(dst∈m2); m0 = m1 ∪ src(dst∈m1)
    mark_set <<<1, NG, 0, stream>>>(fidx, m2, m1);
    mark_srcs<<<EB, 256, 0, stream>>>(src, dst, m2, m1);
    mark_srcs<<<EB, 256, 0, stream>>>(src, dst, m1, m0);
    mask_or  <<<NB, 256, 0, stream>>>(m0, m1);
    compact2 <<<NB, 256, 0, stream>>>(m0, m1, list0, list1, n0, n1);

    // fused CSR build: 1 count pass + batched scan + 1 bucket pass
    fused_count<<<EB, 256, 0, stream>>>(src, dst, m0, m1, m2, indeg,
                                        cnt3, cnt3 + N_NODES, cnt3 + 2 * N_NODES);
    scan_block3<<<3 * NB, 256, 0, stream>>>(cnt3, rp3, bsums3);
    scan_top3  <<<3, 512, 0, stream>>>(bsums3);
    add_offsets3<<<3 * NB, 256, 0, stream>>>(rp3, bsums3, cnt3);
    fused_bucket<<<EB, 256, 0, stream>>>(src, dst, m0, m1, m2, rp3,
                                         cur0, cur1, cur2, esp0, esp1, esp2);

    // layer 0: push dst∈m0, finish on m0 list
    sage_push      <<<N_NODES / TM, 256, 0, stream>>>(x, rp3, esp0, agg);
    sage_finish_sel<<<N_NODES / TM, 256, 0, stream>>>(x, agg, indeg, list0, n0,
                                                      h1, Wl0, bl0, Wr0, 1);
    // layer 1: push dst∈m1, finish on m1 list
    sage_push      <<<N_NODES / TM, 256, 0, stream>>>(h1, rp3 + RPSTR, esp1, agg);
    sage_finish_sel<<<N_NODES / TM, 256, 0, stream>>>(h1, agg, indeg, list1, n1,
                                                      h2, Wl1, bl1, Wr1, 1);
    // layer 2: push dst∈m2, GEMM on the 256 output nodes
    sage_push      <<<N_NODES / TM, 256, 0, stream>>>(h2, rp3 + 2 * RPSTR, esp2, agg);
    final_gemm_sel <<<NG / TM, 256, 0, stream>>>(h2, agg, indeg, fidx, Wl2, bl2, Wr2, out);
}